// Round 4
// baseline (235.387 us; speedup 1.0000x reference)
//
#include <hip/hip_runtime.h>
#include <hip/hip_bf16.h>

typedef __attribute__((ext_vector_type(8))) short short8;
typedef __attribute__((ext_vector_type(4))) float floatx4;

#define N_BI 256
#define N_BS 256
#define LI 36
#define LS 30

// CHW=32 (no pad): X chunk = 36*64 = 2304 B, Y chunk = 30*64 = 1920 B.
// Global/LDS layout XOR-swizzled: inner = (row*64 + cc*2) ^ ((row&7)<<4).
constexpr int XCK   = 2304;
constexpr int YCK   = 1920;
constexpr int XSTEP = 2 * XCK;                // 4608 B per i per k-step (h+l)
constexpr int YSTEP = 2 * YCK;                // 3840 B per j per k-step
constexpr int IBK = 4, JBK = 4;
constexpr int XBLK = IBK * XSTEP;             // 18432
constexpr int YBLK = JBK * YSTEP;             // 15360
constexpr int TB   = XBLK + YBLK;             // 33792 B per k-step buffer
constexpr int XUNITS = XBLK / 16;             // 1152
constexpr int UNITS  = TB / 16;               // 2112

constexpr long long X2_BYTES = (long long)N_BI * 8 * XSTEP;
constexpr long long Y2_BYTES = (long long)N_BS * 8 * YSTEP;
constexpr long long X2_OFF = 32768;
constexpr long long Y2_OFF = X2_OFF + X2_BYTES;

__device__ __forceinline__ void gld16(const void* g, void* l) {
  __builtin_amdgcn_global_load_lds(
      (const __attribute__((address_space(1))) void*)(g),
      (__attribute__((address_space(3))) void*)(unsigned int)(unsigned long long)(l),
      16, 0, 0);
}

// ---- precompute: bf16 hi/lo split into swizzled chunked layout (verified R3) ----
__global__ void adl_build_x2(const float* __restrict__ src, char* __restrict__ dst) {
  long long e = (long long)blockIdx.x * 256 + threadIdx.x;
  if (e >= (long long)N_BI * 8 * 2 * LI * 32) return;
  int cc = (int)(e & 31);
  long long t = e >> 5;
  int p  = (int)(t % LI); t /= LI;
  int hl = (int)(t & 1);  t >>= 1;
  int kc = (int)(t & 7);
  int i  = (int)(t >> 3);
  float x = src[((long long)i * 37 + p + 1) * 256 + kc * 32 + cc];
  float hf = __bfloat162float(__float2bfloat16(x));
  float v = hl ? (x - hf) : hf;
  long long db = ((long long)(i * 8 + kc) * 2 + hl) * XCK +
                 ((p * 64 + cc * 2) ^ ((p & 7) << 4));
  *(__hip_bfloat16*)(dst + db) = __float2bfloat16(v);
}

__global__ void adl_build_y2(const float* __restrict__ src, char* __restrict__ dst) {
  long long e = (long long)blockIdx.x * 256 + threadIdx.x;
  if (e >= (long long)N_BS * 8 * 2 * LS * 32) return;
  int cc = (int)(e & 31);
  long long t = e >> 5;
  int q  = (int)(t % LS); t /= LS;
  int hl = (int)(t & 1);  t >>= 1;
  int kc = (int)(t & 7);
  int j  = (int)(t >> 3);
  float y = src[((long long)j * 31 + q + 1) * 256 + kc * 32 + cc];
  float hf = __bfloat162float(__float2bfloat16(y));
  float v = hl ? (y - hf) : hf;
  long long db = ((long long)(j * 8 + kc) * 2 + hl) * YCK +
                 ((q * 64 + cc * 2) ^ ((q & 7) << 4));
  *(__hip_bfloat16*)(dst + db) = __float2bfloat16(v);
}

// ---- main fused kernel: 4 waves, wave = 2i x 2j, 8 k-steps, 3 products ----
__global__ __launch_bounds__(256, 2) void adl_main(
    const char* __restrict__ X2g, const char* __restrict__ Y2g,
    const float* __restrict__ teacher, const int* __restrict__ im_len,
    const int* __restrict__ s_len, double* __restrict__ partials) {
  __shared__ __align__(16) char lds[2 * TB];
  __shared__ double wsum[4];

  const int bid = blockIdx.x;
  const int ig = bid >> 6, jg = bid & 63;
  const int i0 = ig * IBK, j0 = jg * JBK;
  const int tid = (int)threadIdx.x;
  const int w = tid >> 6, l = tid & 63;
  const int iw2 = (w >> 1) * 2;     // wave's first i within block
  const int jw2 = (w & 1) * 2;      // wave's first j within block
  const int col = l & 15, kg = l >> 4;

  floatx4 acc[2][2][3][2];          // [ii][jj][pt][nt]
#pragma unroll
  for (int ii = 0; ii < 2; ++ii)
#pragma unroll
    for (int jj = 0; jj < 2; ++jj)
#pragma unroll
      for (int pt = 0; pt < 3; ++pt)
#pragma unroll
        for (int nt = 0; nt < 2; ++nt)
          acc[ii][jj][pt][nt] = (floatx4){0.f, 0.f, 0.f, 0.f};

  // ---- staging descriptors: 9 slots x 256 threads; dest = u*16 linear ----
  const char* cur[9];
  int str[9];
  char* ldsb[9];
#pragma unroll
  for (int s = 0; s < 9; ++s) {
    int u = s * 256 + tid;
    ldsb[s] = lds + (s * 256 + w * 64) * 16;   // lane-invariant base
    if (u < XUNITS) {
      int ii = u / 288, r = u % 288;
      cur[s] = X2g + (long long)(i0 + ii) * (8 * XSTEP) + r * 16;
      str[s] = XSTEP;
    } else {
      int v = u - XUNITS; v = v < 0 ? 0 : (v > 959 ? 959 : v);
      int jj = v / 240, r = v % 240;
      cur[s] = Y2g + (long long)(j0 + jj) * (8 * YSTEP) + r * 16;
      str[s] = YSTEP;
    }
  }

  auto stage = [&](int bi) {
#pragma unroll
    for (int s = 0; s < 9; ++s) {
      if (s < 8 || w == 0) {          // slot 8 active only for wave 0 (u<2112)
        gld16(cur[s], ldsb[s] + bi * TB);
        cur[s] += str[s];
      }
    }
  };

  // ---- fragment offsets within a tile buffer (h; l = +XCK/+YCK) ----
  int xoh[2][3];
#pragma unroll
  for (int ii = 0; ii < 2; ++ii)
#pragma unroll
    for (int pt = 0; pt < 3; ++pt) {
      int p = pt * 16 + col; p = p > LI - 1 ? LI - 1 : p;
      xoh[ii][pt] = (iw2 + ii) * XSTEP + ((p * 64 + kg * 16) ^ ((p & 7) << 4));
    }
  int yoh[2][2];
#pragma unroll
  for (int jj = 0; jj < 2; ++jj)
#pragma unroll
    for (int nt = 0; nt < 2; ++nt) {
      int q = nt * 16 + col; q = q > LS - 1 ? LS - 1 : q;
      yoh[jj][nt] = XBLK + (jw2 + jj) * YSTEP + ((q * 64 + kg * 16) ^ ((q & 7) << 4));
    }

  // ---- K-loop ----
  stage(0);
  __syncthreads();

#pragma unroll
  for (int kc = 0; kc < 8; ++kc) {
    if (kc < 7) stage((kc + 1) & 1);
    const char* tb = lds + (kc & 1) * TB;

    short8 xh[2][3], yh[2][2];
#pragma unroll
    for (int ii = 0; ii < 2; ++ii)
#pragma unroll
      for (int pt = 0; pt < 3; ++pt) xh[ii][pt] = *(const short8*)(tb + xoh[ii][pt]);
#pragma unroll
    for (int jj = 0; jj < 2; ++jj)
#pragma unroll
      for (int nt = 0; nt < 2; ++nt) yh[jj][nt] = *(const short8*)(tb + yoh[jj][nt]);
    __builtin_amdgcn_s_setprio(1);
#pragma unroll
    for (int ii = 0; ii < 2; ++ii)
#pragma unroll
      for (int jj = 0; jj < 2; ++jj)
#pragma unroll
        for (int pt = 0; pt < 3; ++pt)
#pragma unroll
          for (int nt = 0; nt < 2; ++nt)
            acc[ii][jj][pt][nt] = __builtin_amdgcn_mfma_f32_16x16x32_bf16(
                xh[ii][pt], yh[jj][nt], acc[ii][jj][pt][nt], 0, 0, 0);
    __builtin_amdgcn_s_setprio(0);

    short8 xl[2][3];
#pragma unroll
    for (int ii = 0; ii < 2; ++ii)
#pragma unroll
      for (int pt = 0; pt < 3; ++pt)
        xl[ii][pt] = *(const short8*)(tb + xoh[ii][pt] + XCK);
    __builtin_amdgcn_s_setprio(1);
#pragma unroll
    for (int ii = 0; ii < 2; ++ii)
#pragma unroll
      for (int jj = 0; jj < 2; ++jj)
#pragma unroll
        for (int pt = 0; pt < 3; ++pt)
#pragma unroll
          for (int nt = 0; nt < 2; ++nt)
            acc[ii][jj][pt][nt] = __builtin_amdgcn_mfma_f32_16x16x32_bf16(
                xl[ii][pt], yh[jj][nt], acc[ii][jj][pt][nt], 0, 0, 0);
    __builtin_amdgcn_s_setprio(0);

    short8 yl[2][2];
#pragma unroll
    for (int jj = 0; jj < 2; ++jj)
#pragma unroll
      for (int nt = 0; nt < 2; ++nt)
        yl[jj][nt] = *(const short8*)(tb + yoh[jj][nt] + YCK);
    __builtin_amdgcn_s_setprio(1);
#pragma unroll
    for (int ii = 0; ii < 2; ++ii)
#pragma unroll
      for (int jj = 0; jj < 2; ++jj)
#pragma unroll
        for (int pt = 0; pt < 3; ++pt)
#pragma unroll
          for (int nt = 0; nt < 2; ++nt)
            acc[ii][jj][pt][nt] = __builtin_amdgcn_mfma_f32_16x16x32_bf16(
                xh[ii][pt], yl[jj][nt], acc[ii][jj][pt][nt], 0, 0, 0);
    __builtin_amdgcn_s_setprio(0);

    __syncthreads();   // drains vmcnt(0): stage(kc+1) landed
  }

  // ---- epilogue: per q-row lse + teacher KL, p in-lane (verified math) ----
  const float scale = 0.0625f;  // 1/sqrt(256)
  float part = 0.f;
  const floatx4 Tz = (floatx4){0.f, 0.f, 0.f, 0.f};

#pragma unroll
  for (int ii = 0; ii < 2; ++ii) {
    const int i = i0 + iw2 + ii;
    const int ilim = min(im_len[i] - 1, LI);
#pragma unroll
    for (int jj = 0; jj < 2; ++jj) {
      const int j = j0 + jw2 + jj;
      const int sl = min(s_len[j] - 1, LS);
      const float* Tb = teacher + ((long long)i * N_BS + j) * (LS * LI);
      floatx4 T[2][3];
#pragma unroll
      for (int nt = 0; nt < 2; ++nt) {
        int tq = nt * 16 + col; tq = tq > LS - 1 ? LS - 1 : tq;
        const float* rb = Tb + tq * LI;
        T[nt][0] = *(const floatx4*)(rb + 4 * kg);
        T[nt][1] = *(const floatx4*)(rb + 16 + 4 * kg);
        T[nt][2] = (kg == 0) ? *(const floatx4*)(rb + 32) : Tz;
      }
#pragma unroll
      for (int nt = 0; nt < 2; ++nt) {
        const int q = nt * 16 + col;
        float vv[3][4];
        float mx = -3.0e38f;
#pragma unroll
        for (int pt = 0; pt < 3; ++pt)
#pragma unroll
          for (int r = 0; r < 4; ++r) {
            int p = pt * 16 + 4 * kg + r;
            vv[pt][r] = acc[ii][jj][pt][nt][r] * scale;
            if (p < ilim) mx = fmaxf(mx, vv[pt][r]);
          }
        mx = fmaxf(mx, __shfl_xor(mx, 16));
        mx = fmaxf(mx, __shfl_xor(mx, 32));
        float se = 0.f, S = 0.f, spos = 0.f, tlt = 0.f, cnum = 0.f;
#pragma unroll
        for (int pt = 0; pt < 3; ++pt)
#pragma unroll
          for (int r = 0; r < 4; ++r) {
            int p = pt * 16 + 4 * kg + r;
            bool pv = p < ilim;
            if (pv) se += __expf(vv[pt][r] - mx);
            float tt = T[nt][pt][r];
            S += fabsf(tt);
            if (pv && tt > 0.f) {
              spos += tt;
              tlt += tt * __logf(tt);
              cnum += tt * vv[pt][r];
            }
          }
#pragma unroll
        for (int d = 16; d <= 32; d <<= 1) {
          se   += __shfl_xor(se, d);
          S    += __shfl_xor(S, d);
          spos += __shfl_xor(spos, d);
          tlt  += __shfl_xor(tlt, d);
          cnum += __shfl_xor(cnum, d);
        }
        float lse = mx + __logf(se);
        float Sb = fmaxf(S, 1e-12f);
        float row = (tlt - cnum + (lse - __logf(Sb)) * spos) / Sb;
        if (kg == 0 && q < sl) part += row;
      }
    }
  }

#pragma unroll
  for (int d = 1; d < 64; d <<= 1) part += __shfl_xor(part, d);
  if (l == 0) wsum[w] = (double)part;
  __syncthreads();
  if (tid == 0) {
    double s = 0.0;
#pragma unroll
    for (int k = 0; k < 4; ++k) s += wsum[k];
    partials[bid] = s;
  }
}

// ---- finalize: fixed-order reduction + n_rows ----
__global__ void adl_finalize(const double* __restrict__ partials,
                             const int* __restrict__ s_len, float* __restrict__ out) {
  __shared__ double sd[256];
  __shared__ double sn[256];
  int t = (int)threadIdx.x;
  double s = 0.0;
  for (int k = t; k < 4096; k += 256) s += partials[k];
  sd[t] = s;
  sn[t] = (double)min(s_len[t] - 1, LS);
  __syncthreads();
  for (int step = 128; step > 0; step >>= 1) {
    if (t < step) { sd[t] += sd[t + step]; sn[t] += sn[t + step]; }
    __syncthreads();
  }
  if (t == 0) out[0] = (float)(sd[0] / (sn[0] * 256.0));
}

extern "C" void kernel_launch(void* const* d_in, const int* in_sizes, int n_in,
                              void* d_out, int out_size, void* d_ws, size_t ws_size,
                              hipStream_t stream) {
  (void)in_sizes; (void)n_in; (void)out_size; (void)ws_size;
  const float* im     = (const float*)d_in[0];
  const float* ss     = (const float*)d_in[1];
  const int*   imlen  = (const int*)d_in[2];
  const int*   slen   = (const int*)d_in[3];
  const float* teach  = (const float*)d_in[4];
  float* out = (float*)d_out;
  char* ws = (char*)d_ws;
  double* partials = (double*)ws;
  char* X2 = ws + X2_OFF;
  char* Y2 = ws + Y2_OFF;

  long long xe = (long long)N_BI * 8 * 2 * LI * 32;
  long long ye = (long long)N_BS * 8 * 2 * LS * 32;
  adl_build_x2<<<(int)((xe + 255) / 256), 256, 0, stream>>>(im, X2);
  adl_build_y2<<<(int)((ye + 255) / 256), 256, 0, stream>>>(ss, Y2);
  adl_main<<<4096, 256, 0, stream>>>(X2, Y2, teach, imlen, slen, partials);
  adl_finalize<<<1, 256, 0, stream>>>(partials, slen, out);
}

// Round 5
// 146.055 us; speedup vs baseline: 1.6116x; 1.6116x over previous
//
#include <hip/hip_runtime.h>
#include <hip/hip_bf16.h>

typedef __attribute__((ext_vector_type(8))) short short8;
typedef __attribute__((ext_vector_type(4))) float floatx4;

#define N_BI 256
#define N_BS 256
#define LI 36
#define LS 30

// Pure-bf16 single product. Chunked swizzled layout:
// X2[i][kc][ (p*64+cc*2)^((p&7)<<4) ], chunk = 36*64 = 2304 B.
// Y2[j][kc][ (q*64+cc*2)^((q&7)<<4) ], chunk = 30*64 = 1920 B.
constexpr int XCK = 2304;
constexpr int YCK = 1920;
constexpr int IBK = 4, JBK = 4;
constexpr int XBLK = IBK * XCK;               // 9216
constexpr int YBLK = JBK * YCK;               // 7680
constexpr int TB   = XBLK + YBLK;             // 16896 B per k-step buffer
constexpr int XUNITS = XBLK / 16;             // 576
constexpr int UNITS  = TB / 16;               // 1056

constexpr long long X2_BYTES = (long long)N_BI * 8 * XCK;   // 4,718,592
constexpr long long Y2_BYTES = (long long)N_BS * 8 * YCK;   // 3,932,160
constexpr long long X2_OFF = 32768;
constexpr long long Y2_OFF = X2_OFF + X2_BYTES;

__device__ __forceinline__ void gld16(const void* g, void* l) {
  __builtin_amdgcn_global_load_lds(
      (const __attribute__((address_space(1))) void*)(g),
      (__attribute__((address_space(3))) void*)(unsigned int)(unsigned long long)(l),
      16, 0, 0);
}

// ---- precompute: bf16 round-to-nearest, swizzled chunk layout ----
__global__ void adl_build_x2(const float* __restrict__ src, char* __restrict__ dst) {
  long long e = (long long)blockIdx.x * 256 + threadIdx.x;
  if (e >= (long long)N_BI * 8 * LI * 32) return;
  int cc = (int)(e & 31);
  long long t = e >> 5;
  int p  = (int)(t % LI); t /= LI;
  int kc = (int)(t & 7);
  int i  = (int)(t >> 3);
  float x = src[((long long)i * 37 + p + 1) * 256 + kc * 32 + cc];
  long long db = (long long)(i * 8 + kc) * XCK + ((p * 64 + cc * 2) ^ ((p & 7) << 4));
  *(__hip_bfloat16*)(dst + db) = __float2bfloat16(x);
}

__global__ void adl_build_y2(const float* __restrict__ src, char* __restrict__ dst) {
  long long e = (long long)blockIdx.x * 256 + threadIdx.x;
  if (e >= (long long)N_BS * 8 * LS * 32) return;
  int cc = (int)(e & 31);
  long long t = e >> 5;
  int q  = (int)(t % LS); t /= LS;
  int kc = (int)(t & 7);
  int j  = (int)(t >> 3);
  float y = src[((long long)j * 31 + q + 1) * 256 + kc * 32 + cc];
  long long db = (long long)(j * 8 + kc) * YCK + ((q * 64 + cc * 2) ^ ((q & 7) << 4));
  *(__hip_bfloat16*)(dst + db) = __float2bfloat16(y);
}

// ---- main fused kernel: 8 waves (wave = 1i x 2j), 8 k-steps, 1 product ----
__global__ __launch_bounds__(512, 4) void adl_main(
    const char* __restrict__ X2g, const char* __restrict__ Y2g,
    const float* __restrict__ teacher, const int* __restrict__ im_len,
    const int* __restrict__ s_len, double* __restrict__ partials) {
  __shared__ __align__(16) char lds[2 * TB];
  __shared__ double wsum[8];

  const int bid = blockIdx.x;
  const int ig = bid >> 6, jg = bid & 63;
  const int i0 = ig * IBK, j0 = jg * JBK;
  const int tid = (int)threadIdx.x;
  const int w = tid >> 6, l = tid & 63;
  const int iw = w >> 1;            // wave's i within block
  const int jw0 = (w & 1) * 2;      // wave's first j within block
  const int col = l & 15, kg = l >> 4;

  floatx4 acc[2][3][2];             // [jj][pt][nt]
#pragma unroll
  for (int jj = 0; jj < 2; ++jj)
#pragma unroll
    for (int pt = 0; pt < 3; ++pt)
#pragma unroll
      for (int nt = 0; nt < 2; ++nt)
        acc[jj][pt][nt] = (floatx4){0.f, 0.f, 0.f, 0.f};

  // ---- staging: 3 slots x 512 threads; dest = u*16 linear (wave-uniform base) ----
  const char* cur[3];
  int str[3];
  char* ldsb[3];
#pragma unroll
  for (int s = 0; s < 3; ++s) {
    int u = s * 512 + tid;
    ldsb[s] = lds + (s * 512 + w * 64) * 16;   // lane-invariant base
    if (u < XUNITS) {
      int ii = u / 144, r = u % 144;
      cur[s] = X2g + (long long)(i0 + ii) * (8 * XCK) + r * 16;
      str[s] = XCK;
    } else {
      int v = u - XUNITS; v = v < 0 ? 0 : (v > 479 ? 479 : v);
      int jj = v / 120, r = v % 120;
      cur[s] = Y2g + (long long)(j0 + jj) * (8 * YCK) + r * 16;
      str[s] = YCK;
    }
  }

  auto stage = [&](int bi) {
#pragma unroll
    for (int s = 0; s < 3; ++s) {
      if (s < 2 || (w == 0 && l < 32)) {   // slot 2: units 1024..1055 only
        gld16(cur[s], ldsb[s] + bi * TB);
        cur[s] += str[s];
      }
    }
  };

  // ---- fragment offsets within a tile buffer ----
  int xoh[3];
#pragma unroll
  for (int pt = 0; pt < 3; ++pt) {
    int p = pt * 16 + col; p = p > LI - 1 ? LI - 1 : p;
    xoh[pt] = iw * XCK + ((p * 64 + kg * 16) ^ ((p & 7) << 4));
  }
  int yoh[2][2];
#pragma unroll
  for (int jj = 0; jj < 2; ++jj)
#pragma unroll
    for (int nt = 0; nt < 2; ++nt) {
      int q = nt * 16 + col; q = q > LS - 1 ? LS - 1 : q;
      yoh[jj][nt] = XBLK + (jw0 + jj) * YCK + ((q * 64 + kg * 16) ^ ((q & 7) << 4));
    }

  // ---- K-loop: 8 steps, 1 product, barrier per step (last step barrier-free) ----
  stage(0);
  __syncthreads();

#pragma unroll
  for (int kc = 0; kc < 8; ++kc) {
    if (kc < 7) stage((kc + 1) & 1);
    const char* tb = lds + (kc & 1) * TB;

    short8 xf[3], yf[2][2];
#pragma unroll
    for (int pt = 0; pt < 3; ++pt) xf[pt] = *(const short8*)(tb + xoh[pt]);
#pragma unroll
    for (int jj = 0; jj < 2; ++jj)
#pragma unroll
      for (int nt = 0; nt < 2; ++nt) yf[jj][nt] = *(const short8*)(tb + yoh[jj][nt]);
    __builtin_amdgcn_s_setprio(1);
#pragma unroll
    for (int jj = 0; jj < 2; ++jj)
#pragma unroll
      for (int pt = 0; pt < 3; ++pt)
#pragma unroll
        for (int nt = 0; nt < 2; ++nt)
          acc[jj][pt][nt] = __builtin_amdgcn_mfma_f32_16x16x32_bf16(
              xf[pt], yf[jj][nt], acc[jj][pt][nt], 0, 0, 0);
    __builtin_amdgcn_s_setprio(0);

    if (kc < 7) __syncthreads();   // drains vmcnt(0): stage(kc+1) landed
  }

  // ---- epilogue: per q-row lse + teacher KL, p in-lane (verified math) ----
  const float scale = 0.0625f;  // 1/sqrt(256)
  const int i = i0 + iw;
  const int ilim = min(im_len[i] - 1, LI);
  float part = 0.f;
  const floatx4 Tz = (floatx4){0.f, 0.f, 0.f, 0.f};

#pragma unroll
  for (int jj = 0; jj < 2; ++jj) {
    const int j = j0 + jw0 + jj;
    const int sl = min(s_len[j] - 1, LS);
    const float* Tb = teacher + ((long long)i * N_BS + j) * (LS * LI);
    floatx4 T[2][3];
#pragma unroll
    for (int nt = 0; nt < 2; ++nt) {
      int tq = nt * 16 + col; tq = tq > LS - 1 ? LS - 1 : tq;
      const float* rb = Tb + tq * LI;
      T[nt][0] = *(const floatx4*)(rb + 4 * kg);
      T[nt][1] = *(const floatx4*)(rb + 16 + 4 * kg);
      T[nt][2] = (kg == 0) ? *(const floatx4*)(rb + 32) : Tz;
    }
#pragma unroll
    for (int nt = 0; nt < 2; ++nt) {
      const int q = nt * 16 + col;
      float vv[3][4];
      float mx = -3.0e38f;
#pragma unroll
      for (int pt = 0; pt < 3; ++pt)
#pragma unroll
        for (int r = 0; r < 4; ++r) {
          int p = pt * 16 + 4 * kg + r;
          vv[pt][r] = acc[jj][pt][nt][r] * scale;
          if (p < ilim) mx = fmaxf(mx, vv[pt][r]);
        }
      mx = fmaxf(mx, __shfl_xor(mx, 16));
      mx = fmaxf(mx, __shfl_xor(mx, 32));
      float se = 0.f, S = 0.f, spos = 0.f, tlt = 0.f, cnum = 0.f;
#pragma unroll
      for (int pt = 0; pt < 3; ++pt)
#pragma unroll
        for (int r = 0; r < 4; ++r) {
          int p = pt * 16 + 4 * kg + r;
          bool pv = p < ilim;
          if (pv) se += __expf(vv[pt][r] - mx);
          float tt = T[nt][pt][r];
          S += fabsf(tt);
          if (pv && tt > 0.f) {
            spos += tt;
            tlt += tt * __logf(tt);
            cnum += tt * vv[pt][r];
          }
        }
#pragma unroll
      for (int d = 16; d <= 32; d <<= 1) {
        se   += __shfl_xor(se, d);
        S    += __shfl_xor(S, d);
        spos += __shfl_xor(spos, d);
        tlt  += __shfl_xor(tlt, d);
        cnum += __shfl_xor(cnum, d);
      }
      float lse = mx + __logf(se);
      float Sb = fmaxf(S, 1e-12f);
      float row = (tlt - cnum + (lse - __logf(Sb)) * spos) / Sb;
      if (kg == 0 && q < sl) part += row;
    }
  }

#pragma unroll
  for (int d = 1; d < 64; d <<= 1) part += __shfl_xor(part, d);
  if (l == 0) wsum[w] = (double)part;
  __syncthreads();
  if (tid == 0) {
    double s = 0.0;
#pragma unroll
    for (int k = 0; k < 8; ++k) s += wsum[k];
    partials[bid] = s;
  }
}

// ---- finalize: fixed-order reduction + n_rows ----
__global__ void adl_finalize(const double* __restrict__ partials,
                             const int* __restrict__ s_len, float* __restrict__ out) {
  __shared__ double sd[256];
  __shared__ double sn[256];
  int t = (int)threadIdx.x;
  double s = 0.0;
  for (int k = t; k < 4096; k += 256) s += partials[k];
  sd[t] = s;
  sn[t] = (double)min(s_len[t] - 1, LS);
  __syncthreads();
  for (int step = 128; step > 0; step >>= 1) {
    if (t < step) { sd[t] += sd[t + step]; sn[t] += sn[t + step]; }
    __syncthreads();
  }
  if (t == 0) out[0] = (float)(sd[0] / (sn[0] * 256.0));
}

extern "C" void kernel_launch(void* const* d_in, const int* in_sizes, int n_in,
                              void* d_out, int out_size, void* d_ws, size_t ws_size,
                              hipStream_t stream) {
  (void)in_sizes; (void)n_in; (void)out_size; (void)ws_size;
  const float* im     = (const float*)d_in[0];
  const float* ss     = (const float*)d_in[1];
  const int*   imlen  = (const int*)d_in[2];
  const int*   slen   = (const int*)d_in[3];
  const float* teach  = (const float*)d_in[4];
  float* out = (float*)d_out;
  char* ws = (char*)d_ws;
  double* partials = (double*)ws;
  char* X2 = ws + X2_OFF;
  char* Y2 = ws + Y2_OFF;

  long long xe = (long long)N_BI * 8 * LI * 32;
  long long ye = (long long)N_BS * 8 * LS * 32;
  adl_build_x2<<<(int)((xe + 255) / 256), 256, 0, stream>>>(im, X2);
  adl_build_y2<<<(int)((ye + 255) / 256), 256, 0, stream>>>(ss, Y2);
  adl_main<<<4096, 512, 0, stream>>>(X2, Y2, teach, imlen, slen, partials);
  adl_finalize<<<1, 256, 0, stream>>>(partials, slen, out);
}